// Round 3
// baseline (1191.806 us; speedup 1.0000x reference)
//
#include <hip/hip_runtime.h>

// Koopman operator: z' = z + DT*(z@A^T + ((z@Vf)*a)@Uf), 8 steps fused.
// Column-parallel, weight-register-stationary, software-pipelined schedule:
//   block = 512 threads = 8 waves, 64 rows/block, 1 block/CU (reg-bound).
//   Wave w owns output col-tiles {2w, 2w+1}; waves 0..5 own one proj tile.
//   Step loop: [bar A] phase1 (zf double-buffered reads under MFMA, p writes)
//              [bar B] phase2 (pf pipelined reads, MFMA, FUSED z-scatter for
//              the next step hidden under phase-2 MFMA shadow).
//   2 barriers/step; no standalone scatter pass.

typedef __bf16 bf16_t;
typedef __bf16 bf16x8 __attribute__((ext_vector_type(8)));
typedef float f32x4 __attribute__((ext_vector_type(4)));

#define DT_C   0.1f
#define BMAX_C 0.3f

#define ZP 264   // z_lds row pitch (elems)
#define PP 104   // p_lds row pitch

#define WT1_ELEMS (352 * 256)
#define WT2_ELEMS (256 * 96)

// ---------------- dtype detector --------------------------------------------
__global__ void detect_dtype(const unsigned int* __restrict__ Abits,
                             int* __restrict__ flag) {
  if (threadIdx.x == 0 && blockIdx.x == 0) {
    int plausible = 0;
    for (int i = 0; i < 64; ++i) {
      unsigned int w = Abits[i];
      int e0 = (int)((w >> 7) & 0xFFu);
      int e1 = (int)((w >> 23) & 0xFFu);
      plausible += (e0 >= 100 && e0 <= 133);
      plausible += (e1 >= 100 && e1 <= 133);
    }
    *flag = (plausible >= 112) ? 1 : 0;  // 1 = bf16 storage, 0 = fp32
  }
}

// ---------------- prep: fold tanh clamp + DT into transposed bf16 weights ---
template <typename T, int MODE>
__global__ __launch_bounds__(256) void prep_weights(
    const int* __restrict__ flag, const T* __restrict__ A,
    const T* __restrict__ BU, const T* __restrict__ BV,
    bf16_t* __restrict__ wt1, bf16_t* __restrict__ wt2) {
  if (*flag != MODE) return;
  int idx = blockIdx.x * 256 + threadIdx.x;
  if (idx < WT1_ELEMS) {
    int i = idx >> 8;          // 0..351
    int j = idx & 255;
    float v;
    if (i < 256) {
      v = DT_C * (float)A[i * 256 + j];
    } else {
      int c = i - 256, l = c >> 4, r = c & 15;
      v = BMAX_C * tanhf((float)BV[(l * 256 + j) * 16 + r]);
    }
    wt1[idx] = (bf16_t)v;
  } else {
    int k = idx - WT1_ELEMS;
    if (k < WT2_ELEMS) {
      int i = k / 96, c = k % 96;
      int l = c >> 4, r = c & 15;
      wt2[k] = (bf16_t)(DT_C * BMAX_C * tanhf((float)BU[(l * 256 + i) * 16 + r]));
    }
  }
}

// ---------------- fused 8-step propagation ----------------------------------
template <typename T, int MODE>
__global__ __launch_bounds__(512, 2) void koopman_kernel(
    const int* __restrict__ flag, const T* __restrict__ zg,
    const T* __restrict__ ag, const int* __restrict__ steps_p,
    const bf16_t* __restrict__ wt1, const bf16_t* __restrict__ wt2,
    T* __restrict__ outg) {
  if (*flag != MODE) return;

  __shared__ __align__(16) bf16_t z_lds[64 * ZP];
  __shared__ __align__(16) bf16_t p_lds[64 * PP];

  const int tid = threadIdx.x;
  const int wave = tid >> 6;       // 0..7
  const int lane = tid & 63;
  const int col = lane & 15;       // MFMA n / C-col
  const int quad = lane >> 4;      // MFMA lane quad
  const long long row0 = (long long)blockIdx.x * 64;
  const int ct0 = wave * 2;        // owned col-tiles: ct0, ct0+1

  // ---- weight fragments: register-resident for the whole kernel ----------
  bf16x8 w1f[3][8];   // [0]/[1]: A^T tiles ct0/ct0+1; [2]: proj tile (wave<6)
  bf16x8 w2f[2][3];
#pragma unroll
  for (int kk = 0; kk < 8; ++kk) {
    w1f[0][kk] = *(const bf16x8*)&wt1[(size_t)(ct0 * 16 + col) * 256 + kk * 32 + quad * 8];
    w1f[1][kk] = *(const bf16x8*)&wt1[(size_t)((ct0 + 1) * 16 + col) * 256 + kk * 32 + quad * 8];
  }
  if (wave < 6) {
#pragma unroll
    for (int kk = 0; kk < 8; ++kk)
      w1f[2][kk] = *(const bf16x8*)&wt1[(size_t)(256 + wave * 16 + col) * 256 + kk * 32 + quad * 8];
  }
#pragma unroll
  for (int kk = 0; kk < 3; ++kk) {
    w2f[0][kk] = *(const bf16x8*)&wt2[(size_t)(ct0 * 16 + col) * 96 + kk * 32 + quad * 8];
    w2f[1][kk] = *(const bf16x8*)&wt2[(size_t)((ct0 + 1) * 16 + col) * 96 + kk * 32 + quad * 8];
  }

  // ---- a-scales for this wave's proj tile (a is step-invariant) ----------
  float ascale[16];
  if (wave < 6) {
#pragma unroll
    for (int rg = 0; rg < 4; ++rg)
#pragma unroll
      for (int reg = 0; reg < 4; ++reg)
        ascale[rg * 4 + reg] =
            (float)ag[(row0 + rg * 16 + quad * 4 + reg) * 6 + wave];
  }

  // ---- z master: fp32 C-layout regs for owned col-tiles, all 64 rows -----
  f32x4 zacc[2][4];
#pragma unroll
  for (int t = 0; t < 2; ++t)
#pragma unroll
    for (int rg = 0; rg < 4; ++rg)
#pragma unroll
      for (int reg = 0; reg < 4; ++reg)
        zacc[t][rg][reg] =
            (float)zg[(row0 + rg * 16 + quad * 4 + reg) * 256 + (ct0 + t) * 16 + col];

  const int steps = steps_p[0];

#define SCATTER_RG(rg_)                                                       \
  {                                                                           \
    _Pragma("unroll") for (int t = 0; t < 2; ++t)                             \
        _Pragma("unroll") for (int reg = 0; reg < 4; ++reg)                   \
            z_lds[((rg_)*16 + quad * 4 + reg) * ZP + (ct0 + t) * 16 + col] =  \
                (bf16_t)zacc[t][rg_][reg];                                    \
  }

#define LOAD_ZF(dst, rg_)                                                     \
  {                                                                           \
    _Pragma("unroll") for (int kk = 0; kk < 8; ++kk)(dst)[kk] =               \
        *(const bf16x8*)&z_lds[((rg_)*16 + col) * ZP + kk * 32 + quad * 8];   \
  }

#define LOAD_PF(dst, rg_)                                                     \
  {                                                                           \
    _Pragma("unroll") for (int kk = 0; kk < 3; ++kk)(dst)[kk] =               \
        *(const bf16x8*)&p_lds[((rg_)*16 + col) * PP + kk * 32 + quad * 8];   \
  }

  // prologue: scatter initial z
  SCATTER_RG(0); SCATTER_RG(1); SCATTER_RG(2); SCATTER_RG(3);

  for (int s = 0; s < steps; ++s) {
    __syncthreads();  // (A) all z_lds writes of this step visible

    // ---- phase 1: z @ Wt1 over 4 row-groups, zf double-buffered -----------
    bf16x8 zbufA[8], zbufB[8];
    LOAD_ZF(zbufA, 0);
#pragma unroll
    for (int rg = 0; rg < 4; ++rg) {
      const bf16x8* zf = (rg & 1) ? zbufB : zbufA;
      bf16x8* znx = (rg & 1) ? zbufA : zbufB;
      if (rg < 3) LOAD_ZF(znx, rg + 1);  // next rg's reads issued before MFMA
      f32x4 a0 = zacc[0][rg], a1 = zacc[1][rg];
      f32x4 pr = {0.f, 0.f, 0.f, 0.f};
      __builtin_amdgcn_s_setprio(1);
      if (wave < 6) {
#pragma unroll
        for (int kk = 0; kk < 8; ++kk) {  // 3-way chain interleave
          a0 = __builtin_amdgcn_mfma_f32_16x16x32_bf16(zf[kk], w1f[0][kk], a0, 0, 0, 0);
          a1 = __builtin_amdgcn_mfma_f32_16x16x32_bf16(zf[kk], w1f[1][kk], a1, 0, 0, 0);
          pr = __builtin_amdgcn_mfma_f32_16x16x32_bf16(zf[kk], w1f[2][kk], pr, 0, 0, 0);
        }
      } else {
#pragma unroll
        for (int kk = 0; kk < 8; ++kk) {
          a0 = __builtin_amdgcn_mfma_f32_16x16x32_bf16(zf[kk], w1f[0][kk], a0, 0, 0, 0);
          a1 = __builtin_amdgcn_mfma_f32_16x16x32_bf16(zf[kk], w1f[1][kk], a1, 0, 0, 0);
        }
      }
      __builtin_amdgcn_s_setprio(0);
      zacc[0][rg] = a0;
      zacc[1][rg] = a1;
      if (wave < 6) {
#pragma unroll
        for (int reg = 0; reg < 4; ++reg)
          p_lds[(rg * 16 + quad * 4 + reg) * PP + wave * 16 + col] =
              (bf16_t)(pr[reg] * ascale[rg * 4 + reg]);
      }
    }
    __syncthreads();  // (B) p visible; all zf reads of this step complete

    // ---- phase 2: z += (proj*a) @ Wt2 (K=96), fused next-step scatter -----
    bf16x8 pbufA[3], pbufB[3];
    LOAD_PF(pbufA, 0);
#pragma unroll
    for (int rg = 0; rg < 4; ++rg) {
      const bf16x8* pf = (rg & 1) ? pbufB : pbufA;
      bf16x8* pnx = (rg & 1) ? pbufA : pbufB;
      if (rg < 3) LOAD_PF(pnx, rg + 1);
      f32x4 a0 = zacc[0][rg], a1 = zacc[1][rg];
      __builtin_amdgcn_s_setprio(1);
#pragma unroll
      for (int kk = 0; kk < 3; ++kk) {
        a0 = __builtin_amdgcn_mfma_f32_16x16x32_bf16(pf[kk], w2f[0][kk], a0, 0, 0, 0);
        a1 = __builtin_amdgcn_mfma_f32_16x16x32_bf16(pf[kk], w2f[1][kk], a1, 0, 0, 0);
      }
      __builtin_amdgcn_s_setprio(0);
      zacc[0][rg] = a0;
      zacc[1][rg] = a1;
      // fused scatter of updated rg rows for the next step (safe: all zf
      // reads of this step completed before barrier (B)).
      SCATTER_RG(rg);
    }
  }

  // ---- epilogue: direct C-layout stores in native dtype -------------------
#pragma unroll
  for (int t = 0; t < 2; ++t)
#pragma unroll
    for (int rg = 0; rg < 4; ++rg)
#pragma unroll
      for (int reg = 0; reg < 4; ++reg)
        outg[(row0 + rg * 16 + quad * 4 + reg) * 256 + (ct0 + t) * 16 + col] =
            (T)zacc[t][rg][reg];
#undef SCATTER_RG
#undef LOAD_ZF
#undef LOAD_PF
}

extern "C" void kernel_launch(void* const* d_in, const int* in_sizes, int n_in,
                              void* d_out, int out_size, void* d_ws,
                              size_t ws_size, hipStream_t stream) {
  const void* z = d_in[0];
  const void* a = d_in[1];
  const void* A = d_in[2];
  const void* BU = d_in[3];
  const void* BV = d_in[4];
  const int* steps = (const int*)d_in[5];

  int* flag = (int*)d_ws;
  bf16_t* wt1 = (bf16_t*)((char*)d_ws + 16);
  bf16_t* wt2 = wt1 + WT1_ELEMS;

  const int N = in_sizes[0] / 256;  // 262144 rows

  detect_dtype<<<1, 64, 0, stream>>>((const unsigned int*)A, flag);

  prep_weights<float, 0><<<448, 256, 0, stream>>>(
      flag, (const float*)A, (const float*)BU, (const float*)BV, wt1, wt2);
  prep_weights<bf16_t, 1><<<448, 256, 0, stream>>>(
      flag, (const bf16_t*)A, (const bf16_t*)BU, (const bf16_t*)BV, wt1, wt2);

  koopman_kernel<float, 0><<<N / 64, 512, 0, stream>>>(
      flag, (const float*)z, (const float*)a, steps, wt1, wt2, (float*)d_out);
  koopman_kernel<bf16_t, 1><<<N / 64, 512, 0, stream>>>(
      flag, (const bf16_t*)z, (const bf16_t*)a, steps, wt1, wt2,
      (bf16_t*)d_out);
}

// Round 4
// 901.090 us; speedup vs baseline: 1.3226x; 1.3226x over previous
//
#include <hip/hip_runtime.h>

// Koopman operator: z' = z + DT*(z@A^T + ((z@Vf)*a)@Uf), 8 steps fused.
// Column-parallel, weight-register-stationary, REGISTER-NEUTRAL pipelining:
//   block = 512 threads = 8 waves, 64 rows/block, ~240 unified regs/wave
//   -> 2 waves/SIMD, 1 block/CU (reg-bound; launch_bounds(512,2) caps 256).
//   Wave w owns output col-tiles {2w, 2w+1}; waves 0..5 own one proj tile.
//   Phase 1: flat 8-unit half-rg pipeline, zb0[4]/zb1[4] ping-pong (same 32
//   regs as the old serial zf[8]) so ds_read_b128 of unit u+1 fly under unit
//   u's MFMAs. Phase 2: pf ping-pong + fused next-step z-scatter.
//   a-scales live in LDS (saves 16 regs to pay for pf ping-pong).

typedef __bf16 bf16_t;
typedef __bf16 bf16x8 __attribute__((ext_vector_type(8)));
typedef float f32x4 __attribute__((ext_vector_type(4)));

#define DT_C   0.1f
#define BMAX_C 0.3f

#define ZP 264   // z_lds row pitch (elems)
#define PP 104   // p_lds row pitch
#define AP 9     // a_lds row pitch (floats; 9 breaks the row-stride-4 bank hit)

#define WT1_ELEMS (352 * 256)
#define WT2_ELEMS (256 * 96)

// ---------------- dtype detector --------------------------------------------
__global__ void detect_dtype(const unsigned int* __restrict__ Abits,
                             int* __restrict__ flag) {
  if (threadIdx.x == 0 && blockIdx.x == 0) {
    int plausible = 0;
    for (int i = 0; i < 64; ++i) {
      unsigned int w = Abits[i];
      int e0 = (int)((w >> 7) & 0xFFu);
      int e1 = (int)((w >> 23) & 0xFFu);
      plausible += (e0 >= 100 && e0 <= 133);
      plausible += (e1 >= 100 && e1 <= 133);
    }
    *flag = (plausible >= 112) ? 1 : 0;  // 1 = bf16 storage, 0 = fp32
  }
}

// ---------------- prep: fold tanh clamp + DT into transposed bf16 weights ---
template <typename T, int MODE>
__global__ __launch_bounds__(256) void prep_weights(
    const int* __restrict__ flag, const T* __restrict__ A,
    const T* __restrict__ BU, const T* __restrict__ BV,
    bf16_t* __restrict__ wt1, bf16_t* __restrict__ wt2) {
  if (*flag != MODE) return;
  int idx = blockIdx.x * 256 + threadIdx.x;
  if (idx < WT1_ELEMS) {
    int i = idx >> 8;          // 0..351
    int j = idx & 255;
    float v;
    if (i < 256) {
      v = DT_C * (float)A[i * 256 + j];
    } else {
      int c = i - 256, l = c >> 4, r = c & 15;
      v = BMAX_C * tanhf((float)BV[(l * 256 + j) * 16 + r]);
    }
    wt1[idx] = (bf16_t)v;
  } else {
    int k = idx - WT1_ELEMS;
    if (k < WT2_ELEMS) {
      int i = k / 96, c = k % 96;
      int l = c >> 4, r = c & 15;
      wt2[k] = (bf16_t)(DT_C * BMAX_C * tanhf((float)BU[(l * 256 + i) * 16 + r]));
    }
  }
}

// ---------------- fused 8-step propagation ----------------------------------
template <typename T, int MODE>
__global__ __launch_bounds__(512, 2) void koopman_kernel(
    const int* __restrict__ flag, const T* __restrict__ zg,
    const T* __restrict__ ag, const int* __restrict__ steps_p,
    const bf16_t* __restrict__ wt1, const bf16_t* __restrict__ wt2,
    T* __restrict__ outg) {
  if (*flag != MODE) return;

  __shared__ __align__(16) bf16_t z_lds[64 * ZP];
  __shared__ __align__(16) bf16_t p_lds[64 * PP];
  __shared__ float a_lds[64 * AP];

  const int tid = threadIdx.x;
  const int wave = tid >> 6;       // 0..7
  const int lane = tid & 63;
  const int col = lane & 15;       // MFMA n / C-col
  const int quad = lane >> 4;      // MFMA lane quad
  const long long row0 = (long long)blockIdx.x * 64;
  const int ct0 = wave * 2;        // owned col-tiles: ct0, ct0+1

  // ---- stage a into LDS (fp32, step-invariant) ---------------------------
  for (int t = tid; t < 64 * 6; t += 512) {
    int r = t / 6, l = t % 6;
    a_lds[r * AP + l] = (float)ag[(row0 + r) * 6 + l];
  }

  // ---- weight fragments: register-resident for the whole kernel ----------
  bf16x8 w1f[3][8];   // [0]/[1]: A^T tiles ct0/ct0+1; [2]: proj tile (wave<6)
  bf16x8 w2f[2][3];
#pragma unroll
  for (int kk = 0; kk < 8; ++kk) {
    w1f[0][kk] = *(const bf16x8*)&wt1[(size_t)(ct0 * 16 + col) * 256 + kk * 32 + quad * 8];
    w1f[1][kk] = *(const bf16x8*)&wt1[(size_t)((ct0 + 1) * 16 + col) * 256 + kk * 32 + quad * 8];
  }
  if (wave < 6) {
#pragma unroll
    for (int kk = 0; kk < 8; ++kk)
      w1f[2][kk] = *(const bf16x8*)&wt1[(size_t)(256 + wave * 16 + col) * 256 + kk * 32 + quad * 8];
  }
#pragma unroll
  for (int kk = 0; kk < 3; ++kk) {
    w2f[0][kk] = *(const bf16x8*)&wt2[(size_t)(ct0 * 16 + col) * 96 + kk * 32 + quad * 8];
    w2f[1][kk] = *(const bf16x8*)&wt2[(size_t)((ct0 + 1) * 16 + col) * 96 + kk * 32 + quad * 8];
  }

  // ---- z master: fp32 C-layout regs for owned col-tiles, all 64 rows -----
  f32x4 zacc[2][4];
#pragma unroll
  for (int t = 0; t < 2; ++t)
#pragma unroll
    for (int rg = 0; rg < 4; ++rg)
#pragma unroll
      for (int reg = 0; reg < 4; ++reg)
        zacc[t][rg][reg] =
            (float)zg[(row0 + rg * 16 + quad * 4 + reg) * 256 + (ct0 + t) * 16 + col];

  const int steps = steps_p[0];

#define SCATTER_RG(rg_)                                                       \
  {                                                                           \
    _Pragma("unroll") for (int t = 0; t < 2; ++t)                             \
        _Pragma("unroll") for (int reg = 0; reg < 4; ++reg)                   \
            z_lds[((rg_)*16 + quad * 4 + reg) * ZP + (ct0 + t) * 16 + col] =  \
                (bf16_t)zacc[t][rg_][reg];                                    \
  }

// load 4 zf frags (half h of row-group rg) into dst[0..3]
#define LOADZ4(dst, rg_, h_)                                                  \
  {                                                                           \
    _Pragma("unroll") for (int kk = 0; kk < 4; ++kk)(dst)[kk] =               \
        *(const bf16x8*)&z_lds[((rg_)*16 + col) * ZP + ((h_)*4 + kk) * 32 +   \
                               quad * 8];                                     \
  }

#define LOADP3(dst, rg_)                                                      \
  {                                                                           \
    _Pragma("unroll") for (int kk = 0; kk < 3; ++kk)(dst)[kk] =               \
        *(const bf16x8*)&p_lds[((rg_)*16 + col) * PP + kk * 32 + quad * 8];   \
  }

  // prologue: scatter initial z
  SCATTER_RG(0); SCATTER_RG(1); SCATTER_RG(2); SCATTER_RG(3);

  for (int s = 0; s < steps; ++s) {
    __syncthreads();  // (A) z_lds writes + (first iter) a_lds visible

    // ---- phase 1: z @ Wt1, flat 8-unit half-rg pipeline -------------------
    bf16x8 zb0[4], zb1[4];
    LOADZ4(zb0, 0, 0);
    f32x4 a0, a1, pr;
    float asc0, asc1, asc2, asc3;
#pragma unroll
    for (int u = 0; u < 8; ++u) {
      const int rg = u >> 1;
      const int half = u & 1;
      // prefetch next unit's 4 frags into the other buffer
      if (u < 7) {
        if (u & 1) { LOADZ4(zb0, (u + 1) >> 1, (u + 1) & 1); }
        else       { LOADZ4(zb1, (u + 1) >> 1, (u + 1) & 1); }
      }
      if (half == 0) {
        a0 = zacc[0][rg];
        a1 = zacc[1][rg];
        pr = (f32x4){0.f, 0.f, 0.f, 0.f};
        if (wave < 6) {  // a-scales for this rg, hidden under the MFMAs below
          asc0 = a_lds[(rg * 16 + quad * 4 + 0) * AP + wave];
          asc1 = a_lds[(rg * 16 + quad * 4 + 1) * AP + wave];
          asc2 = a_lds[(rg * 16 + quad * 4 + 2) * AP + wave];
          asc3 = a_lds[(rg * 16 + quad * 4 + 3) * AP + wave];
        }
      }
      const bf16x8* zf = (u & 1) ? zb1 : zb0;
      __builtin_amdgcn_s_setprio(1);
      if (wave < 6) {
#pragma unroll
        for (int kk = 0; kk < 4; ++kk) {  // 3-way chain interleave
          a0 = __builtin_amdgcn_mfma_f32_16x16x32_bf16(zf[kk], w1f[0][half * 4 + kk], a0, 0, 0, 0);
          a1 = __builtin_amdgcn_mfma_f32_16x16x32_bf16(zf[kk], w1f[1][half * 4 + kk], a1, 0, 0, 0);
          pr = __builtin_amdgcn_mfma_f32_16x16x32_bf16(zf[kk], w1f[2][half * 4 + kk], pr, 0, 0, 0);
        }
      } else {
#pragma unroll
        for (int kk = 0; kk < 4; ++kk) {
          a0 = __builtin_amdgcn_mfma_f32_16x16x32_bf16(zf[kk], w1f[0][half * 4 + kk], a0, 0, 0, 0);
          a1 = __builtin_amdgcn_mfma_f32_16x16x32_bf16(zf[kk], w1f[1][half * 4 + kk], a1, 0, 0, 0);
        }
      }
      __builtin_amdgcn_s_setprio(0);
      if (half == 1) {
        zacc[0][rg] = a0;
        zacc[1][rg] = a1;
        if (wave < 6) {
          p_lds[(rg * 16 + quad * 4 + 0) * PP + wave * 16 + col] = (bf16_t)(pr[0] * asc0);
          p_lds[(rg * 16 + quad * 4 + 1) * PP + wave * 16 + col] = (bf16_t)(pr[1] * asc1);
          p_lds[(rg * 16 + quad * 4 + 2) * PP + wave * 16 + col] = (bf16_t)(pr[2] * asc2);
          p_lds[(rg * 16 + quad * 4 + 3) * PP + wave * 16 + col] = (bf16_t)(pr[3] * asc3);
        }
      }
    }
    __syncthreads();  // (B) p visible; all zf reads of this step complete

    // ---- phase 2: z += (proj*a) @ Wt2 (K=96), pf ping-pong + fused scatter
    bf16x8 pb0[3], pb1[3];
    LOADP3(pb0, 0);
#pragma unroll
    for (int rg = 0; rg < 4; ++rg) {
      if (rg < 3) {
        if (rg & 1) { LOADP3(pb0, rg + 1); }
        else        { LOADP3(pb1, rg + 1); }
      }
      const bf16x8* pf = (rg & 1) ? pb1 : pb0;
      f32x4 b0 = zacc[0][rg], b1 = zacc[1][rg];
      __builtin_amdgcn_s_setprio(1);
#pragma unroll
      for (int kk = 0; kk < 3; ++kk) {
        b0 = __builtin_amdgcn_mfma_f32_16x16x32_bf16(pf[kk], w2f[0][kk], b0, 0, 0, 0);
        b1 = __builtin_amdgcn_mfma_f32_16x16x32_bf16(pf[kk], w2f[1][kk], b1, 0, 0, 0);
      }
      __builtin_amdgcn_s_setprio(0);
      zacc[0][rg] = b0;
      zacc[1][rg] = b1;
      // fused scatter of updated rg rows for the next step (safe: all zf
      // reads of this step completed before barrier (B)).
      SCATTER_RG(rg);
    }
  }

  // ---- epilogue: direct C-layout stores in native dtype -------------------
#pragma unroll
  for (int t = 0; t < 2; ++t)
#pragma unroll
    for (int rg = 0; rg < 4; ++rg)
#pragma unroll
      for (int reg = 0; reg < 4; ++reg)
        outg[(row0 + rg * 16 + quad * 4 + reg) * 256 + (ct0 + t) * 16 + col] =
            (T)zacc[t][rg][reg];
#undef SCATTER_RG
#undef LOADZ4
#undef LOADP3
}

extern "C" void kernel_launch(void* const* d_in, const int* in_sizes, int n_in,
                              void* d_out, int out_size, void* d_ws,
                              size_t ws_size, hipStream_t stream) {
  const void* z = d_in[0];
  const void* a = d_in[1];
  const void* A = d_in[2];
  const void* BU = d_in[3];
  const void* BV = d_in[4];
  const int* steps = (const int*)d_in[5];

  int* flag = (int*)d_ws;
  bf16_t* wt1 = (bf16_t*)((char*)d_ws + 16);
  bf16_t* wt2 = wt1 + WT1_ELEMS;

  const int N = in_sizes[0] / 256;  // 262144 rows

  detect_dtype<<<1, 64, 0, stream>>>((const unsigned int*)A, flag);

  prep_weights<float, 0><<<448, 256, 0, stream>>>(
      flag, (const float*)A, (const float*)BU, (const float*)BV, wt1, wt2);
  prep_weights<bf16_t, 1><<<448, 256, 0, stream>>>(
      flag, (const bf16_t*)A, (const bf16_t*)BU, (const bf16_t*)BV, wt1, wt2);

  koopman_kernel<float, 0><<<N / 64, 512, 0, stream>>>(
      flag, (const float*)z, (const float*)a, steps, wt1, wt2, (float*)d_out);
  koopman_kernel<bf16_t, 1><<<N / 64, 512, 0, stream>>>(
      flag, (const bf16_t*)z, (const bf16_t*)a, steps, wt1, wt2,
      (bf16_t*)d_out);
}